// Round 1
// baseline (412.548 us; speedup 1.0000x reference)
//
#include <hip/hip_runtime.h>
#include <math.h>

#define NBATCH 256

// ================= GEMM + sigmoid + avgpool2 =================
// Y[b, p] = 0.5*( sig(dot(A[b,:], W[2p,:])   + bias[2p])
//               + sig(dot(A[b,:], W[2p+1,:]) + bias[2p+1]) )
// A: (256, K) row-major, W: (N, K) row-major, bias: (N), Y: (256, N/2)
// Block tile: 64 i x 32 b, K-tile 32, 256 threads, micro-tile 4i x 2b.

#define TI 64
#define TB 32
#define TK 32
#define LDW 68   // TI + 4 pad (keeps 16B alignment, breaks bank conflicts)
#define LDX 36   // TB + 4 pad

__global__ __launch_bounds__(256) void gemm_sig_pool(
    const float* __restrict__ A, const float* __restrict__ W,
    const float* __restrict__ bias, float* __restrict__ Y,
    int K, int Np /* = N/2 */) {
  __shared__ float Ws[TK][LDW];
  __shared__ float Xs[TK][LDX];
  const int tid = threadIdx.x;
  const int ti = tid & 15;   // i micro index (4 i's each)
  const int tb = tid >> 4;   // b micro index (2 b's each)
  const int i_base = blockIdx.x * TI;
  const int b_base = blockIdx.y * TB;

  const int c = tid & 7;     // k float4 slot within tile
  const int r = tid >> 3;    // 0..31 row slot

  float acc[4][2] = {};

  for (int k0 = 0; k0 < K; k0 += TK) {
    // ---- stage tiles ----
    {
      const float4 w0 = *(const float4*)&W[(size_t)(i_base + r) * K + k0 + 4 * c];
      const float4 w1 = *(const float4*)&W[(size_t)(i_base + r + 32) * K + k0 + 4 * c];
      Ws[4 * c + 0][r] = w0.x; Ws[4 * c + 1][r] = w0.y;
      Ws[4 * c + 2][r] = w0.z; Ws[4 * c + 3][r] = w0.w;
      Ws[4 * c + 0][r + 32] = w1.x; Ws[4 * c + 1][r + 32] = w1.y;
      Ws[4 * c + 2][r + 32] = w1.z; Ws[4 * c + 3][r + 32] = w1.w;
      const float4 xv = *(const float4*)&A[(size_t)(b_base + r) * K + k0 + 4 * c];
      Xs[4 * c + 0][r] = xv.x; Xs[4 * c + 1][r] = xv.y;
      Xs[4 * c + 2][r] = xv.z; Xs[4 * c + 3][r] = xv.w;
    }
    __syncthreads();
    // ---- compute ----
#pragma unroll
    for (int k = 0; k < TK; k++) {
      const float4 wv = *(const float4*)&Ws[k][ti * 4];   // 4-lane broadcast groups
      const float2 xv = *(const float2*)&Xs[k][tb * 2];
      acc[0][0] += wv.x * xv.x; acc[0][1] += wv.x * xv.y;
      acc[1][0] += wv.y * xv.x; acc[1][1] += wv.y * xv.y;
      acc[2][0] += wv.z * xv.x; acc[2][1] += wv.z * xv.y;
      acc[3][0] += wv.w * xv.x; acc[3][1] += wv.w * xv.y;
    }
    __syncthreads();
  }

  // ---- epilogue: bias, sigmoid, pool pairs along i ----
  const int i0 = i_base + ti * 4;
  float b0 = bias[i0 + 0], b1 = bias[i0 + 1], b2 = bias[i0 + 2], b3 = bias[i0 + 3];
#pragma unroll
  for (int v = 0; v < 2; v++) {
    const int b = b_base + tb * 2 + v;
    const float a0 = 1.f / (1.f + expf(-(acc[0][v] + b0)));
    const float a1 = 1.f / (1.f + expf(-(acc[1][v] + b1)));
    const float a2 = 1.f / (1.f + expf(-(acc[2][v] + b2)));
    const float a3 = 1.f / (1.f + expf(-(acc[3][v] + b3)));
    Y[(size_t)b * Np + (i0 >> 1) + 0] = 0.5f * (a0 + a1);
    Y[(size_t)b * Np + (i0 >> 1) + 1] = 0.5f * (a2 + a3);
  }
}

// ================= LSTM tail (only s3[:, -1] matters) =================
// One workgroup per batch element. Gate thread g (0..399) holds Whh[g, 0:100]
// permanently in registers; per step it reads the 100-float h vector from LDS
// (wave-uniform broadcast b128 reads -> ~free) and does 100 FMAs, then applies
// its own gate activation (sigmoid for i,f,o; tanh for g, unified as
// m*sigmoid(k*z)+d to avoid divergence). Threads 0..99 then combine gates into
// the c/h update (c lives in their registers).

#define HID 100
#define GATES 400
#define TSTEPS 256
#define LSTM_THREADS 448

__global__ __launch_bounds__(LSTM_THREADS) void lstm_tail(
    const float* __restrict__ X,     // (256, 256) = xl2
    const float* __restrict__ Wih,   // (400,)
    const float* __restrict__ Whh,   // (400, 100)
    const float* __restrict__ bg,    // (400,)
    const float* __restrict__ Wout,  // (100,)
    const float* __restrict__ bout,  // (1,)
    float* __restrict__ out) {       // (256,)
  const int b = blockIdx.x;
  const int t = threadIdx.x;
  __shared__ __align__(16) float hbuf[2][HID];  // double-buffered h
  __shared__ float zs[GATES];
  __shared__ float xrow[TSTEPS];

  for (int i = t; i < TSTEPS; i += LSTM_THREADS) xrow[i] = X[(size_t)b * TSTEPS + i];

  float w[HID];
  float wih = 0.f, bb = 0.f;
  float k_act = 1.f, m_act = 1.f, d_act = 0.f;
  if (t < GATES) {
#pragma unroll
    for (int k = 0; k < HID; k += 4) {
      *(float4*)&w[k] = *(const float4*)&Whh[(size_t)t * HID + k];
    }
    wih = Wih[t];
    bb = bg[t];
    if (t >= 200 && t < 300) { k_act = 2.f; m_act = 2.f; d_act = -1.f; }  // tanh = 2*sig(2z)-1
  }
  if (t < HID) hbuf[0][t] = 0.f;
  float c = 0.f;
  __syncthreads();

  for (int step = 0; step < TSTEPS; step++) {
    const int cur = step & 1;
    if (t < GATES) {
      float z0 = 0.f, z1 = 0.f, z2 = 0.f, z3 = 0.f;
#pragma unroll
      for (int k = 0; k < HID; k += 4) {
        const float4 hv = *(const float4*)&hbuf[cur][k];  // broadcast
        z0 += w[k + 0] * hv.x;
        z1 += w[k + 1] * hv.y;
        z2 += w[k + 2] * hv.z;
        z3 += w[k + 3] * hv.w;
      }
      const float z = ((z0 + z1) + (z2 + z3)) + xrow[step] * wih + bb;
      zs[t] = m_act / (1.f + expf(-k_act * z)) + d_act;
    }
    __syncthreads();
    if (t < HID) {
      const float ai = zs[t], af = zs[t + 100], ag = zs[t + 200], ao = zs[t + 300];
      c = af * c + ai * ag;
      hbuf[cur ^ 1][t] = ao * tanhf(c);
    }
    __syncthreads();
  }

  // final h is in hbuf[0] (TSTEPS even). out[b] = dot(h, Wout) + bout
  if (t < HID) zs[t] = hbuf[0][t] * Wout[t];
  __syncthreads();
  if (t == 0) {
    float s = 0.f;
#pragma unroll
    for (int k = 0; k < HID; k++) s += zs[k];
    out[b] = s + bout[0];
  }
}

// ================= launch =================
extern "C" void kernel_launch(void* const* d_in, const int* in_sizes, int n_in,
                              void* d_out, int out_size, void* d_ws, size_t ws_size,
                              hipStream_t stream) {
  // setup_inputs order:
  // 0:x 1:W1H 2:b1H 3:W1L 4:b1L 5:W2H 6:b2H 7:W2L 8:b2L
  // 9:Wih1 10:Whh1 11:b1 12:Wih2 13:Whh2 14:b2 15:Wih3 16:Whh3 17:b3 18:Wout 19:bout
  const float* x    = (const float*)d_in[0];   // (256,1024,1) == (256,1024)
  const float* W1L  = (const float*)d_in[3];   // (1024,1024)
  const float* b1L  = (const float*)d_in[4];   // (1024,)
  const float* W2L  = (const float*)d_in[7];   // (512,512)
  const float* b2L  = (const float*)d_in[8];   // (512,)
  const float* Wih3 = (const float*)d_in[15];  // (400,1)
  const float* Whh3 = (const float*)d_in[16];  // (400,100)
  const float* b3   = (const float*)d_in[17];  // (400,)
  const float* Wout = (const float*)d_in[18];  // (1,100)
  const float* bout = (const float*)d_in[19];  // (1,)
  float* out = (float*)d_out;                  // (256,1)

  float* xl1 = (float*)d_ws;                         // (256,512)  512 KB
  float* xl2 = (float*)((char*)d_ws + (size_t)256 * 512 * sizeof(float));  // (256,256) 256 KB

  // Stage 1: xl1 = avgpool2(sigmoid(x @ W1L^T + b1L))   N=1024, K=1024
  {
    dim3 grid(1024 / TI, NBATCH / TB);
    gemm_sig_pool<<<grid, 256, 0, stream>>>(x, W1L, b1L, xl1, 1024, 512);
  }
  // Stage 2: xl2 = avgpool2(sigmoid(xl1 @ W2L^T + b2L)) N=512, K=512
  {
    dim3 grid(512 / TI, NBATCH / TB);
    gemm_sig_pool<<<grid, 256, 0, stream>>>(xl1, W2L, b2L, xl2, 512, 256);
  }
  // Stage 3: LSTM3 over xl2, emit out = h_final @ Wout^T + bout
  lstm_tail<<<NBATCH, LSTM_THREADS, 0, stream>>>(xl2, Wih3, Whh3, b3, Wout, bout, out);
}

// Round 2
// 391.974 us; speedup vs baseline: 1.0525x; 1.0525x over previous
//
#include <hip/hip_runtime.h>
#include <math.h>

typedef __bf16 bf16x8 __attribute__((ext_vector_type(8)));
typedef float f32x4 __attribute__((ext_vector_type(4)));

__device__ __forceinline__ unsigned short f2bf(float f) {
  unsigned int u = __builtin_bit_cast(unsigned int, f);
  u += 0x7fffu + ((u >> 16) & 1u);
  return (unsigned short)(u >> 16);
}

// ---------- fp32 -> bf16 conversion for W1L, W2L, x ----------
__global__ __launch_bounds__(256) void convert3(
    const float* __restrict__ s0, const float* __restrict__ s1,
    const float* __restrict__ s2, unsigned short* __restrict__ d0,
    unsigned short* __restrict__ d1, unsigned short* __restrict__ d2,
    int n0, int n1, int n2) {
  int i4 = (blockIdx.x * 256 + threadIdx.x) * 4;
  const float* s; unsigned short* d; int off;
  if (i4 < n0) { s = s0; d = d0; off = i4; }
  else if (i4 < n0 + n1) { s = s1; d = d1; off = i4 - n0; }
  else if (i4 < n0 + n1 + n2) { s = s2; d = d2; off = i4 - n0 - n1; }
  else return;
  float4 v = *(const float4*)&s[off];
  ushort4 o = { f2bf(v.x), f2bf(v.y), f2bf(v.z), f2bf(v.w) };
  *(ushort4*)&d[off] = o;
}

// ---------- bf16 MFMA GEMM + sigmoid + avgpool2 ----------
#define GK_PADK 40
__global__ __launch_bounds__(256) void gemm_mfma_sig_pool(
    const unsigned short* __restrict__ W, const float* __restrict__ bias,
    const unsigned short* __restrict__ X, void* __restrict__ Y,
    int K, int Np, int out_bf16) {
  __shared__ unsigned short Wt[64][GK_PADK];
  __shared__ unsigned short Xt[64][GK_PADK];
  const int tid = threadIdx.x;
  const int i_base = blockIdx.x * 64;
  const int b_base = blockIdx.y * 64;
  const int srow = tid >> 2, sseg = tid & 3;
  const int wv = tid >> 6, lane = tid & 63;
  const int wn = wv & 1, wb = wv >> 1;
  const int L15 = lane & 15, q = lane >> 4;

  f32x4 acc[2][2] = {};
  for (int k0 = 0; k0 < K; k0 += 32) {
    *(uint4*)&Wt[srow][sseg * 8] =
        *(const uint4*)&W[(size_t)(i_base + srow) * K + k0 + sseg * 8];
    *(uint4*)&Xt[srow][sseg * 8] =
        *(const uint4*)&X[(size_t)(b_base + srow) * K + k0 + sseg * 8];
    __syncthreads();
    bf16x8 a0 = *(const bf16x8*)&Wt[wn * 32 + L15][q * 8];
    bf16x8 a1 = *(const bf16x8*)&Wt[wn * 32 + 16 + L15][q * 8];
    bf16x8 b0 = *(const bf16x8*)&Xt[wb * 32 + L15][q * 8];
    bf16x8 b1 = *(const bf16x8*)&Xt[wb * 32 + 16 + L15][q * 8];
    acc[0][0] = __builtin_amdgcn_mfma_f32_16x16x32_bf16(a0, b0, acc[0][0], 0, 0, 0);
    acc[0][1] = __builtin_amdgcn_mfma_f32_16x16x32_bf16(a0, b1, acc[0][1], 0, 0, 0);
    acc[1][0] = __builtin_amdgcn_mfma_f32_16x16x32_bf16(a1, b0, acc[1][0], 0, 0, 0);
    acc[1][1] = __builtin_amdgcn_mfma_f32_16x16x32_bf16(a1, b1, acc[1][1], 0, 0, 0);
    __syncthreads();
  }

  const int nb0 = i_base + wn * 32;
  const int bc0 = b_base + wb * 32 + L15;
#pragma unroll
  for (int mg = 0; mg < 2; mg++) {
    const int nrow = nb0 + mg * 16 + q * 4;
    const float bi0 = bias[nrow], bi1 = bias[nrow + 1];
    const float bi2 = bias[nrow + 2], bi3 = bias[nrow + 3];
#pragma unroll
    for (int bg = 0; bg < 2; bg++) {
      const int b = bc0 + bg * 16;
      f32x4 A = acc[mg][bg];
      const float a0 = 1.f / (1.f + expf(-(A[0] + bi0)));
      const float a1 = 1.f / (1.f + expf(-(A[1] + bi1)));
      const float a2 = 1.f / (1.f + expf(-(A[2] + bi2)));
      const float a3 = 1.f / (1.f + expf(-(A[3] + bi3)));
      const float p0 = 0.5f * (a0 + a1), p1 = 0.5f * (a2 + a3);
      const int pidx = nrow >> 1;  // even
      if (out_bf16) {
        unsigned int pk = (unsigned int)f2bf(p0) | ((unsigned int)f2bf(p1) << 16);
        *(unsigned int*)&((unsigned short*)Y)[(size_t)b * Np + pidx] = pk;
      } else {
        *(float2*)&((float*)Y)[(size_t)b * Np + pidx] = make_float2(p0, p1);
      }
    }
  }
}

// ---------- LSTM tail (only s3[:, -1] matters) ----------
#define HID 100
#define TSTEPS 256

__device__ __forceinline__ float dpp_xadd1(float x) {
  int v = __builtin_amdgcn_mov_dpp(__builtin_bit_cast(int, x), 0xB1, 0xf, 0xf, true);
  return x + __builtin_bit_cast(float, v);
}
__device__ __forceinline__ float dpp_xadd2(float x) {
  int v = __builtin_amdgcn_mov_dpp(__builtin_bit_cast(int, x), 0x4E, 0xf, 0xf, true);
  return x + __builtin_bit_cast(float, v);
}

__global__ __launch_bounds__(448, 1) void lstm_tail(
    const float* __restrict__ X, const float* __restrict__ Wih,
    const float* __restrict__ Whh, const float* __restrict__ bg,
    const float* __restrict__ Wout, const float* __restrict__ bout,
    float* __restrict__ out) {
  const int bat = blockIdx.x;
  const int t = threadIdx.x;
  const int g = t >> 2, kq = t & 3;
  const bool act = (g < 100);
  const int koff = 24 * kq;
  __shared__ __align__(16) float hbuf[2][HID];
  __shared__ __align__(16) float zs[400];
  __shared__ float xrow[TSTEPS];

  for (int i = t; i < TSTEPS; i += 448) xrow[i] = X[(size_t)bat * TSTEPS + i];

  float w[4][28];
  float bias4[4], wih4[4];
  float k_act = 1.f, m_act = 1.f, d_act = 0.f;
  if (act) {
#pragma unroll
    for (int j = 0; j < 4; j++) {
      const int row = 4 * g + j;
#pragma unroll
      for (int qq = 0; qq < 7; qq++) {
        float4 wv = *(const float4*)&Whh[(size_t)row * HID + koff + 4 * qq];
        w[j][4 * qq + 0] = wv.x; w[j][4 * qq + 1] = wv.y;
        w[j][4 * qq + 2] = wv.z; w[j][4 * qq + 3] = wv.w;
      }
      bias4[j] = bg[row];
      wih4[j] = Wih[row];
    }
    if (kq > 0) {
#pragma unroll
      for (int j = 0; j < 4; j++) { w[j][0] = 0.f; w[j][1] = 0.f; w[j][2] = 0.f; w[j][3] = 0.f; }
    }
    if (g >= 50 && g < 75) { k_act = 2.f; m_act = 2.f; d_act = -1.f; }  // tanh
  } else {
#pragma unroll
    for (int j = 0; j < 4; j++) {
      bias4[j] = 0.f; wih4[j] = 0.f;
#pragma unroll
      for (int kk = 0; kk < 28; kk++) w[j][kk] = 0.f;
    }
  }
  if (t < HID) hbuf[0][t] = 0.f;
  float c = 0.f;
  __syncthreads();

  for (int step = 0; step < TSTEPS; step++) {
    const int cur = step & 1;
    float z0 = 0.f, z1 = 0.f, z2 = 0.f, z3 = 0.f;
#pragma unroll
    for (int qq = 0; qq < 7; qq++) {
      const float4 hv = *(const float4*)&hbuf[cur][koff + 4 * qq];
      z0 += w[0][4*qq] * hv.x + w[0][4*qq+1] * hv.y + w[0][4*qq+2] * hv.z + w[0][4*qq+3] * hv.w;
      z1 += w[1][4*qq] * hv.x + w[1][4*qq+1] * hv.y + w[1][4*qq+2] * hv.z + w[1][4*qq+3] * hv.w;
      z2 += w[2][4*qq] * hv.x + w[2][4*qq+1] * hv.y + w[2][4*qq+2] * hv.z + w[2][4*qq+3] * hv.w;
      z3 += w[3][4*qq] * hv.x + w[3][4*qq+1] * hv.y + w[3][4*qq+2] * hv.z + w[3][4*qq+3] * hv.w;
    }
    z0 = dpp_xadd2(dpp_xadd1(z0));
    z1 = dpp_xadd2(dpp_xadd1(z1));
    z2 = dpp_xadd2(dpp_xadd1(z2));
    z3 = dpp_xadd2(dpp_xadd1(z3));
    if (act) {
      const float xv = xrow[step];
      float4 zw;
      zw.x = m_act / (1.f + expf(-k_act * (z0 + bias4[0] + wih4[0] * xv))) + d_act;
      zw.y = m_act / (1.f + expf(-k_act * (z1 + bias4[1] + wih4[1] * xv))) + d_act;
      zw.z = m_act / (1.f + expf(-k_act * (z2 + bias4[2] + wih4[2] * xv))) + d_act;
      zw.w = m_act / (1.f + expf(-k_act * (z3 + bias4[3] + wih4[3] * xv))) + d_act;
      if (kq == 0) *(float4*)&zs[4 * g] = zw;
    }
    __syncthreads();
    if (t < HID) {
      const float ai = zs[t], af = zs[t + 100], ag = zs[t + 200], ao = zs[t + 300];
      c = af * c + ai * ag;
      hbuf[cur ^ 1][t] = ao * tanhf(c);
    }
    __syncthreads();
  }

  if (t < HID) zs[t] = hbuf[0][t] * Wout[t];
  __syncthreads();
  if (t == 0) {
    float s = 0.f;
#pragma unroll
    for (int k = 0; k < HID; k++) s += zs[k];
    out[bat] = s + bout[0];
  }
}

// ---------- launch ----------
extern "C" void kernel_launch(void* const* d_in, const int* in_sizes, int n_in,
                              void* d_out, int out_size, void* d_ws, size_t ws_size,
                              hipStream_t stream) {
  const float* x    = (const float*)d_in[0];
  const float* W1L  = (const float*)d_in[3];
  const float* b1L  = (const float*)d_in[4];
  const float* W2L  = (const float*)d_in[7];
  const float* b2L  = (const float*)d_in[8];
  const float* Wih3 = (const float*)d_in[15];
  const float* Whh3 = (const float*)d_in[16];
  const float* b3   = (const float*)d_in[17];
  const float* Wout = (const float*)d_in[18];
  const float* bout = (const float*)d_in[19];
  float* out = (float*)d_out;

  unsigned short* W1Lb = (unsigned short*)d_ws;  // 1048576 ushorts
  unsigned short* W2Lb = W1Lb + 1048576;         // 262144
  unsigned short* xb   = W2Lb + 262144;          // 262144
  unsigned short* xl1b = xb + 262144;            // 131072 (256x512 bf16)
  float* xl2 = (float*)(xl1b + 131072);          // 65536 floats (256x256)

  convert3<<<1536, 256, 0, stream>>>(W1L, W2L, x, W1Lb, W2Lb, xb,
                                     1048576, 262144, 262144);
  gemm_mfma_sig_pool<<<dim3(16, 4), 256, 0, stream>>>(W1Lb, b1L, xb, xl1b, 1024, 512, 1);
  gemm_mfma_sig_pool<<<dim3(8, 4), 256, 0, stream>>>(W2Lb, b2L, xl1b, xl2, 512, 256, 0);
  lstm_tail<<<256, 448, 0, stream>>>(xl2, Wih3, Whh3, b3, Wout, bout, out);
}

// Round 3
// 307.376 us; speedup vs baseline: 1.3422x; 1.2752x over previous
//
#include <hip/hip_runtime.h>
#include <math.h>

typedef __bf16 bf16x8 __attribute__((ext_vector_type(8)));
typedef float f32x4 __attribute__((ext_vector_type(4)));

__device__ __forceinline__ unsigned short f2bf(float f) {
  unsigned int u = __builtin_bit_cast(unsigned int, f);
  u += 0x7fffu + ((u >> 16) & 1u);
  return (unsigned short)(u >> 16);
}
__device__ __forceinline__ unsigned int pack2bf(float a, float b) {
  return (unsigned int)f2bf(a) | ((unsigned int)f2bf(b) << 16);
}

// ---------- bf16 MFMA GEMM + sigmoid + avgpool2 (fp32->bf16 staged inline) ----------
// Z[n,b] = dot(W[n,:], X[b,:]) + bias[n]; Y[b,n/2] = 0.5*(sig(Z[2p,b])+sig(Z[2p+1,b]))
#define GK_PADK 40
template <int WFP32, int XFP32>
__global__ __launch_bounds__(256) void gemm_mfma_sig_pool(
    const void* __restrict__ Wv, const float* __restrict__ bias,
    const void* __restrict__ Xv, void* __restrict__ Y,
    int K, int Np, int out_bf16) {
  __shared__ unsigned short Wt[64][GK_PADK];
  __shared__ unsigned short Xt[64][GK_PADK];
  const int tid = threadIdx.x;
  const int i_base = blockIdx.x * 64;
  const int b_base = blockIdx.y * 64;
  const int srow = tid >> 2, sseg = tid & 3;
  const int wv = tid >> 6, lane = tid & 63;
  const int wn = wv & 1, wb = wv >> 1;
  const int L15 = lane & 15, q = lane >> 4;

  f32x4 acc[2][2] = {};
  for (int k0 = 0; k0 < K; k0 += 32) {
    if (WFP32) {
      const float* Wf = (const float*)Wv;
      const float4 a = *(const float4*)&Wf[(size_t)(i_base + srow) * K + k0 + sseg * 8];
      const float4 b = *(const float4*)&Wf[(size_t)(i_base + srow) * K + k0 + sseg * 8 + 4];
      uint4 p = { pack2bf(a.x, a.y), pack2bf(a.z, a.w), pack2bf(b.x, b.y), pack2bf(b.z, b.w) };
      *(uint4*)&Wt[srow][sseg * 8] = p;
    } else {
      *(uint4*)&Wt[srow][sseg * 8] =
          *(const uint4*)&((const unsigned short*)Wv)[(size_t)(i_base + srow) * K + k0 + sseg * 8];
    }
    if (XFP32) {
      const float* Xf = (const float*)Xv;
      const float4 a = *(const float4*)&Xf[(size_t)(b_base + srow) * K + k0 + sseg * 8];
      const float4 b = *(const float4*)&Xf[(size_t)(b_base + srow) * K + k0 + sseg * 8 + 4];
      uint4 p = { pack2bf(a.x, a.y), pack2bf(a.z, a.w), pack2bf(b.x, b.y), pack2bf(b.z, b.w) };
      *(uint4*)&Xt[srow][sseg * 8] = p;
    } else {
      *(uint4*)&Xt[srow][sseg * 8] =
          *(const uint4*)&((const unsigned short*)Xv)[(size_t)(b_base + srow) * K + k0 + sseg * 8];
    }
    __syncthreads();
    bf16x8 a0 = *(const bf16x8*)&Wt[wn * 32 + L15][q * 8];
    bf16x8 a1 = *(const bf16x8*)&Wt[wn * 32 + 16 + L15][q * 8];
    bf16x8 b0 = *(const bf16x8*)&Xt[wb * 32 + L15][q * 8];
    bf16x8 b1 = *(const bf16x8*)&Xt[wb * 32 + 16 + L15][q * 8];
    acc[0][0] = __builtin_amdgcn_mfma_f32_16x16x32_bf16(a0, b0, acc[0][0], 0, 0, 0);
    acc[0][1] = __builtin_amdgcn_mfma_f32_16x16x32_bf16(a0, b1, acc[0][1], 0, 0, 0);
    acc[1][0] = __builtin_amdgcn_mfma_f32_16x16x32_bf16(a1, b0, acc[1][0], 0, 0, 0);
    acc[1][1] = __builtin_amdgcn_mfma_f32_16x16x32_bf16(a1, b1, acc[1][1], 0, 0, 0);
    __syncthreads();
  }

  const int nb0 = i_base + wn * 32;
  const int bc0 = b_base + wb * 32 + L15;
#pragma unroll
  for (int mg = 0; mg < 2; mg++) {
    const int nrow = nb0 + mg * 16 + q * 4;
    const float bi0 = bias[nrow], bi1 = bias[nrow + 1];
    const float bi2 = bias[nrow + 2], bi3 = bias[nrow + 3];
#pragma unroll
    for (int bg = 0; bg < 2; bg++) {
      const int b = bc0 + bg * 16;
      f32x4 A = acc[mg][bg];
      const float a0 = __builtin_amdgcn_rcpf(1.f + __expf(-(A[0] + bi0)));
      const float a1 = __builtin_amdgcn_rcpf(1.f + __expf(-(A[1] + bi1)));
      const float a2 = __builtin_amdgcn_rcpf(1.f + __expf(-(A[2] + bi2)));
      const float a3 = __builtin_amdgcn_rcpf(1.f + __expf(-(A[3] + bi3)));
      const float p0 = 0.5f * (a0 + a1), p1 = 0.5f * (a2 + a3);
      const int pidx = nrow >> 1;  // even
      if (out_bf16) {
        *(unsigned int*)&((unsigned short*)Y)[(size_t)b * Np + pidx] = pack2bf(p0, p1);
      } else {
        *(float2*)&((float*)Y)[(size_t)b * Np + pidx] = make_float2(p0, p1);
      }
    }
  }
}

// ---------- LSTM tail (only s3[:, -1] matters) ----------
// Quad-per-row: lane (4r+j) owns gate j of hidden row r; full Whh row (100
// floats) pinned in VGPRs (amdgpu_waves_per_eu(1,2) -> 256-VGPR budget, no
// spill). h reads are wave-uniform LDS broadcasts; gate exchange via quad-perm
// DPP; c/h replicated across the quad; ONE barrier per step.
#define HID 100
#define TSTEPS 256

__device__ __forceinline__ float qb0(float x) {
  return __builtin_bit_cast(float, __builtin_amdgcn_mov_dpp(__builtin_bit_cast(int, x), 0x00, 0xf, 0xf, true));
}
__device__ __forceinline__ float qb1(float x) {
  return __builtin_bit_cast(float, __builtin_amdgcn_mov_dpp(__builtin_bit_cast(int, x), 0x55, 0xf, 0xf, true));
}
__device__ __forceinline__ float qb2(float x) {
  return __builtin_bit_cast(float, __builtin_amdgcn_mov_dpp(__builtin_bit_cast(int, x), 0xAA, 0xf, 0xf, true));
}
__device__ __forceinline__ float qb3(float x) {
  return __builtin_bit_cast(float, __builtin_amdgcn_mov_dpp(__builtin_bit_cast(int, x), 0xFF, 0xf, 0xf, true));
}

__global__ __launch_bounds__(448) __attribute__((amdgpu_waves_per_eu(1, 2)))
void lstm_tail(
    const float* __restrict__ X, const float* __restrict__ Wih,
    const float* __restrict__ Whh, const float* __restrict__ bg,
    const float* __restrict__ Wout, const float* __restrict__ bout,
    float* __restrict__ out) {
  const int bat = blockIdx.x;
  const int t = threadIdx.x;
  const int r = t >> 2, j = t & 3;        // row, gate (0=i,1=f,2=g,3=o)
  const bool valid = (r < HID);
  const int grow = j * HID + r;           // row in Whh/b/Wih
  __shared__ __align__(16) float hbuf[2][104];
  __shared__ float xrow[TSTEPS];
  __shared__ float red[HID];

  for (int i = t; i < TSTEPS; i += 448) xrow[i] = X[(size_t)bat * TSTEPS + i];

  float w[HID];
  float wih = 0.f, bb = 0.f;
  if (valid) {
#pragma unroll
    for (int q = 0; q < 25; q++) {
      const float4 v = *(const float4*)&Whh[(size_t)grow * HID + 4 * q];
      w[4 * q + 0] = v.x; w[4 * q + 1] = v.y; w[4 * q + 2] = v.z; w[4 * q + 3] = v.w;
    }
    wih = Wih[grow];
    bb = bg[grow];
  } else {
#pragma unroll
    for (int k = 0; k < HID; k++) w[k] = 0.f;
  }
  // gate j==2 is tanh: tanh(z) = 2*sig(2z)-1
  const float kk = (j == 2) ? 2.f : 1.f;
  const float mm = (j == 2) ? 2.f : 1.f;
  const float dd = (j == 2) ? -1.f : 0.f;
  if (t < HID) hbuf[0][t] = 0.f;
  float c = 0.f;
  __syncthreads();

  for (int step = 0; step < TSTEPS; step++) {
    const float* hc = hbuf[step & 1];
    float z0 = 0.f, z1 = 0.f, z2 = 0.f, z3 = 0.f;
#pragma unroll
    for (int q = 0; q < 25; q++) {
      const float4 hv = *(const float4*)&hc[4 * q];  // wave-uniform broadcast
      z0 += w[4 * q + 0] * hv.x;
      z1 += w[4 * q + 1] * hv.y;
      z2 += w[4 * q + 2] * hv.z;
      z3 += w[4 * q + 3] * hv.w;
    }
    const float z = ((z0 + z1) + (z2 + z3)) + wih * xrow[step] + bb;
    const float a = mm * __builtin_amdgcn_rcpf(1.f + __expf(-kk * z)) + dd;
    const float ai = qb0(a), af = qb1(a), ag = qb2(a), ao = qb3(a);
    c = af * c + ai * ag;
    // tanh(c) = 2/(1+exp(-2c)) - 1  (saturates cleanly at +-1)
    const float th = 2.f * __builtin_amdgcn_rcpf(1.f + __expf(-2.f * c)) - 1.f;
    const float h = ao * th;
    if (j == 0 && valid) hbuf[(step & 1) ^ 1][r] = h;
    __syncthreads();
  }

  // final h in hbuf[0] (256 steps even): out[bat] = dot(h, Wout) + bout
  if (t < HID) red[t] = hbuf[0][t] * Wout[t];
  __syncthreads();
  if (t == 0) {
    float s = 0.f;
#pragma unroll
    for (int k = 0; k < HID; k++) s += red[k];
    out[bat] = s + bout[0];
  }
}

// ---------- launch ----------
extern "C" void kernel_launch(void* const* d_in, const int* in_sizes, int n_in,
                              void* d_out, int out_size, void* d_ws, size_t ws_size,
                              hipStream_t stream) {
  const float* x    = (const float*)d_in[0];   // (256,1024)
  const float* W1L  = (const float*)d_in[3];   // (1024,1024)
  const float* b1L  = (const float*)d_in[4];
  const float* W2L  = (const float*)d_in[7];   // (512,512)
  const float* b2L  = (const float*)d_in[8];
  const float* Wih3 = (const float*)d_in[15];  // (400,1)
  const float* Whh3 = (const float*)d_in[16];  // (400,100)
  const float* b3   = (const float*)d_in[17];  // (400,)
  const float* Wout = (const float*)d_in[18];  // (1,100)
  const float* bout = (const float*)d_in[19];  // (1,)
  float* out = (float*)d_out;                  // (256,)

  unsigned short* xl1b = (unsigned short*)d_ws;     // 256x512 bf16 = 256 KB
  float* xl2 = (float*)(xl1b + (size_t)256 * 512);  // 256x256 f32 = 256 KB

  // Stage 1: xl1 = pool(sig(x @ W1L^T + b1L)); W,X fp32 -> bf16 inline; out bf16
  gemm_mfma_sig_pool<1, 1><<<dim3(16, 4), 256, 0, stream>>>(W1L, b1L, x, xl1b, 1024, 512, 1);
  // Stage 2: xl2 = pool(sig(xl1 @ W2L^T + b2L)); W fp32 inline, X bf16; out fp32
  gemm_mfma_sig_pool<1, 0><<<dim3(8, 4), 256, 0, stream>>>(W2L, b2L, xl1b, xl2, 512, 256, 0);
  // Stage 3: LSTM3 over xl2
  lstm_tail<<<256, 448, 0, stream>>>(xl2, Wih3, Whh3, b3, Wout, bout, out);
}

// Round 5
// 281.674 us; speedup vs baseline: 1.4646x; 1.0912x over previous
//
#include <hip/hip_runtime.h>
#include <math.h>

typedef __bf16 bf16x8 __attribute__((ext_vector_type(8)));
typedef float f32x4 __attribute__((ext_vector_type(4)));

__device__ __forceinline__ unsigned short f2bf(float f) {
  unsigned int u = __builtin_bit_cast(unsigned int, f);
  u += 0x7fffu + ((u >> 16) & 1u);
  return (unsigned short)(u >> 16);
}
__device__ __forceinline__ unsigned int pack2bf(float a, float b) {
  return (unsigned int)f2bf(a) | ((unsigned int)f2bf(b) << 16);
}

// ---------- bf16 MFMA GEMM + sigmoid + avgpool2 (fp32->bf16 staged inline) ----------
#define GK_PADK 40
template <int WFP32, int XFP32>
__global__ __launch_bounds__(256) void gemm_mfma_sig_pool(
    const void* __restrict__ Wv, const float* __restrict__ bias,
    const void* __restrict__ Xv, void* __restrict__ Y,
    int K, int Np, int out_bf16) {
  __shared__ unsigned short Wt[64][GK_PADK];
  __shared__ unsigned short Xt[64][GK_PADK];
  const int tid = threadIdx.x;
  const int i_base = blockIdx.x * 64;
  const int b_base = blockIdx.y * 64;
  const int srow = tid >> 2, sseg = tid & 3;
  const int wv = tid >> 6, lane = tid & 63;
  const int wn = wv & 1, wb = wv >> 1;
  const int L15 = lane & 15, q = lane >> 4;

  f32x4 acc[2][2] = {};
  for (int k0 = 0; k0 < K; k0 += 32) {
    if (WFP32) {
      const float* Wf = (const float*)Wv;
      const float4 a = *(const float4*)&Wf[(size_t)(i_base + srow) * K + k0 + sseg * 8];
      const float4 b = *(const float4*)&Wf[(size_t)(i_base + srow) * K + k0 + sseg * 8 + 4];
      uint4 p = { pack2bf(a.x, a.y), pack2bf(a.z, a.w), pack2bf(b.x, b.y), pack2bf(b.z, b.w) };
      *(uint4*)&Wt[srow][sseg * 8] = p;
    } else {
      *(uint4*)&Wt[srow][sseg * 8] =
          *(const uint4*)&((const unsigned short*)Wv)[(size_t)(i_base + srow) * K + k0 + sseg * 8];
    }
    if (XFP32) {
      const float* Xf = (const float*)Xv;
      const float4 a = *(const float4*)&Xf[(size_t)(b_base + srow) * K + k0 + sseg * 8];
      const float4 b = *(const float4*)&Xf[(size_t)(b_base + srow) * K + k0 + sseg * 8 + 4];
      uint4 p = { pack2bf(a.x, a.y), pack2bf(a.z, a.w), pack2bf(b.x, b.y), pack2bf(b.z, b.w) };
      *(uint4*)&Xt[srow][sseg * 8] = p;
    } else {
      *(uint4*)&Xt[srow][sseg * 8] =
          *(const uint4*)&((const unsigned short*)Xv)[(size_t)(b_base + srow) * K + k0 + sseg * 8];
    }
    __syncthreads();
    bf16x8 a0 = *(const bf16x8*)&Wt[wn * 32 + L15][q * 8];
    bf16x8 a1 = *(const bf16x8*)&Wt[wn * 32 + 16 + L15][q * 8];
    bf16x8 b0 = *(const bf16x8*)&Xt[wb * 32 + L15][q * 8];
    bf16x8 b1 = *(const bf16x8*)&Xt[wb * 32 + 16 + L15][q * 8];
    acc[0][0] = __builtin_amdgcn_mfma_f32_16x16x32_bf16(a0, b0, acc[0][0], 0, 0, 0);
    acc[0][1] = __builtin_amdgcn_mfma_f32_16x16x32_bf16(a0, b1, acc[0][1], 0, 0, 0);
    acc[1][0] = __builtin_amdgcn_mfma_f32_16x16x32_bf16(a1, b0, acc[1][0], 0, 0, 0);
    acc[1][1] = __builtin_amdgcn_mfma_f32_16x16x32_bf16(a1, b1, acc[1][1], 0, 0, 0);
    __syncthreads();
  }

  const int nb0 = i_base + wn * 32;
  const int bc0 = b_base + wb * 32 + L15;
#pragma unroll
  for (int mg = 0; mg < 2; mg++) {
    const int nrow = nb0 + mg * 16 + q * 4;
    const float bi0 = bias[nrow], bi1 = bias[nrow + 1];
    const float bi2 = bias[nrow + 2], bi3 = bias[nrow + 3];
#pragma unroll
    for (int bg = 0; bg < 2; bg++) {
      const int b = bc0 + bg * 16;
      f32x4 A = acc[mg][bg];
      const float a0 = __builtin_amdgcn_rcpf(1.f + __expf(-(A[0] + bi0)));
      const float a1 = __builtin_amdgcn_rcpf(1.f + __expf(-(A[1] + bi1)));
      const float a2 = __builtin_amdgcn_rcpf(1.f + __expf(-(A[2] + bi2)));
      const float a3 = __builtin_amdgcn_rcpf(1.f + __expf(-(A[3] + bi3)));
      const float p0 = 0.5f * (a0 + a1), p1 = 0.5f * (a2 + a3);
      const int pidx = nrow >> 1;  // even
      if (out_bf16) {
        *(unsigned int*)&((unsigned short*)Y)[(size_t)b * Np + pidx] = pack2bf(p0, p1);
      } else {
        *(float2*)&((float*)Y)[(size_t)b * Np + pidx] = make_float2(p0, p1);
      }
    }
  }
}

// ---------- LSTM tail ----------
// Lane (r = t>>2, kq = t&3) owns ALL 4 gates of hidden row r over k-quarter
// [25*kq, 25*kq+25). Weights are individually-named SSA float4/float values
// (no array, no alloca -> VGPR residency under waves_per_eu(1,2)'s 256-reg
// budget). h lives in LDS as 4 chunks at 32-float stride so each lane does
// only 7 aligned ds_read_b128 per step. Quad butterfly (DPP 0xB1 + 0x4E)
// completes the dots; activation + c/h update replicated per quad; one
// barrier per step.
#define HID 100
#define TSTEPS 256

__device__ __forceinline__ float qx1(float x) {
  int v = __builtin_amdgcn_mov_dpp(__builtin_bit_cast(int, x), 0xB1, 0xf, 0xf, true);
  return x + __builtin_bit_cast(float, v);
}
__device__ __forceinline__ float qx2(float x) {
  int v = __builtin_amdgcn_mov_dpp(__builtin_bit_cast(int, x), 0x4E, 0xf, 0xf, true);
  return x + __builtin_bit_cast(float, v);
}

__global__ __launch_bounds__(448) __attribute__((amdgpu_waves_per_eu(1, 2)))
void lstm_tail(
    const float* __restrict__ X, const float* __restrict__ Wih,
    const float* __restrict__ Whh, const float* __restrict__ bg,
    const float* __restrict__ Wout, const float* __restrict__ bout,
    float* __restrict__ out) {
  const int bat = blockIdx.x;
  const int t = threadIdx.x;
  const int r = t >> 2;        // hidden row (valid < 100)
  const int kq = t & 3;        // k quarter
  const int koff = 25 * kq;
  const bool valid = (r < HID);
  const int rr = valid ? r : 0;
  __shared__ __align__(16) float hbuf[2][128];
  __shared__ float xrow[TSTEPS];
  __shared__ float red[HID];

  for (int i = t; i < TSTEPS; i += 448) xrow[i] = X[(size_t)bat * TSTEPS + i];

  const float* Wr0 = &Whh[(size_t)(0 * HID + rr) * HID + koff];
  const float* Wr1 = &Whh[(size_t)(1 * HID + rr) * HID + koff];
  const float* Wr2 = &Whh[(size_t)(2 * HID + rr) * HID + koff];
  const float* Wr3 = &Whh[(size_t)(3 * HID + rr) * HID + koff];

#define DECLW(P) float4 P##_0, P##_1, P##_2, P##_3, P##_4, P##_5; float P##_6;
  DECLW(wi) DECLW(wf) DECLW(wg) DECLW(wo)
#undef DECLW
#define LW(P, B)                                      \
  P##_0 = make_float4(B[0],  B[1],  B[2],  B[3]);     \
  P##_1 = make_float4(B[4],  B[5],  B[6],  B[7]);     \
  P##_2 = make_float4(B[8],  B[9],  B[10], B[11]);    \
  P##_3 = make_float4(B[12], B[13], B[14], B[15]);    \
  P##_4 = make_float4(B[16], B[17], B[18], B[19]);    \
  P##_5 = make_float4(B[20], B[21], B[22], B[23]);    \
  P##_6 = B[24];
  LW(wi, Wr0) LW(wf, Wr1) LW(wg, Wr2) LW(wo, Wr3)
#undef LW

  const float bi_ = bg[0 * HID + rr], bf_ = bg[1 * HID + rr];
  const float bg_ = bg[2 * HID + rr], bo_ = bg[3 * HID + rr];
  const float ui = Wih[0 * HID + rr], uf = Wih[1 * HID + rr];
  const float ug = Wih[2 * HID + rr], uo = Wih[3 * HID + rr];

  const int hpos = ((rr / 25) << 5) + (rr % 25);  // h write slot (chunked layout)

  if (t < 128) { hbuf[0][t] = 0.f; hbuf[1][t] = 0.f; }
  float c = 0.f;
  __syncthreads();

  for (int step = 0; step < TSTEPS; step++) {
    const float* hq = &hbuf[step & 1][kq << 5];
    float z0 = 0.f, z1 = 0.f, z2 = 0.f, z3 = 0.f;
#define G4(OFF, WI, WF, WG, WO)                                                  \
    { const float4 h4 = *(const float4*)&hq[OFF];                                \
      z0 = fmaf(WI.x, h4.x, z0); z1 = fmaf(WF.x, h4.x, z1);                      \
      z2 = fmaf(WG.x, h4.x, z2); z3 = fmaf(WO.x, h4.x, z3);                      \
      z0 = fmaf(WI.y, h4.y, z0); z1 = fmaf(WF.y, h4.y, z1);                      \
      z2 = fmaf(WG.y, h4.y, z2); z3 = fmaf(WO.y, h4.y, z3);                      \
      z0 = fmaf(WI.z, h4.z, z0); z1 = fmaf(WF.z, h4.z, z1);                      \
      z2 = fmaf(WG.z, h4.z, z2); z3 = fmaf(WO.z, h4.z, z3);                      \
      z0 = fmaf(WI.w, h4.w, z0); z1 = fmaf(WF.w, h4.w, z1);                      \
      z2 = fmaf(WG.w, h4.w, z2); z3 = fmaf(WO.w, h4.w, z3); }
    G4(0,  wi_0, wf_0, wg_0, wo_0)
    G4(4,  wi_1, wf_1, wg_1, wo_1)
    G4(8,  wi_2, wf_2, wg_2, wo_2)
    G4(12, wi_3, wf_3, wg_3, wo_3)
    G4(16, wi_4, wf_4, wg_4, wo_4)
    G4(20, wi_5, wf_5, wg_5, wo_5)
    { const float h1 = hq[24];
      z0 = fmaf(wi_6, h1, z0); z1 = fmaf(wf_6, h1, z1);
      z2 = fmaf(wg_6, h1, z2); z3 = fmaf(wo_6, h1, z3); }
#undef G4
    // quad butterfly: every lane in the quad ends with the full 100-k sums
    z0 = qx2(qx1(z0)); z1 = qx2(qx1(z1)); z2 = qx2(qx1(z2)); z3 = qx2(qx1(z3));

    const float xt = xrow[step];
    const float zi = fmaf(ui, xt, z0 + bi_);
    const float zf = fmaf(uf, xt, z1 + bf_);
    const float zg = fmaf(ug, xt, z2 + bg_);
    const float zo = fmaf(uo, xt, z3 + bo_);
    const float ai = __builtin_amdgcn_rcpf(1.f + __expf(-zi));
    const float af = __builtin_amdgcn_rcpf(1.f + __expf(-zf));
    const float ag = 2.f * __builtin_amdgcn_rcpf(1.f + __expf(-2.f * zg)) - 1.f;
    const float ao = __builtin_amdgcn_rcpf(1.f + __expf(-zo));
    c = fmaf(af, c, ai * ag);
    const float th = 2.f * __builtin_amdgcn_rcpf(1.f + __expf(-2.f * c)) - 1.f;
    if (kq == 0 && valid) hbuf[(step & 1) ^ 1][hpos] = ao * th;
    __syncthreads();
  }

  if (t < HID) {
    const int mc = t / 25, mr2 = t % 25;
    red[t] = hbuf[0][(mc << 5) + mr2] * Wout[t];
  }
  __syncthreads();
  if (t == 0) {
    float s = 0.f;
#pragma unroll
    for (int k = 0; k < HID; k++) s += red[k];
    out[bat] = s + bout[0];
  }
}

// ---------- launch ----------
extern "C" void kernel_launch(void* const* d_in, const int* in_sizes, int n_in,
                              void* d_out, int out_size, void* d_ws, size_t ws_size,
                              hipStream_t stream) {
  const float* x    = (const float*)d_in[0];   // (256,1024)
  const float* W1L  = (const float*)d_in[3];   // (1024,1024)
  const float* b1L  = (const float*)d_in[4];
  const float* W2L  = (const float*)d_in[7];   // (512,512)
  const float* b2L  = (const float*)d_in[8];
  const float* Wih3 = (const float*)d_in[15];  // (400,1)
  const float* Whh3 = (const float*)d_in[16];  // (400,100)
  const float* b3   = (const float*)d_in[17];  // (400,)
  const float* Wout = (const float*)d_in[18];  // (1,100)
  const float* bout = (const float*)d_in[19];  // (1,)
  float* out = (float*)d_out;                  // (256,)

  unsigned short* xl1b = (unsigned short*)d_ws;     // 256x512 bf16
  float* xl2 = (float*)(xl1b + (size_t)256 * 512);  // 256x256 f32

  gemm_mfma_sig_pool<1, 1><<<dim3(16, 4), 256, 0, stream>>>(W1L, b1L, x, xl1b, 1024, 512, 1);
  gemm_mfma_sig_pool<1, 0><<<dim3(8, 4), 256, 0, stream>>>(W2L, b2L, xl1b, xl2, 512, 256, 0);
  lstm_tail<<<256, 448, 0, stream>>>(xl2, Wih3, Whh3, b3, Wout, bout, out);
}